// Round 4
// baseline (1798.392 us; speedup 1.0000x reference)
//
#include <hip/hip_runtime.h>
#include <hip/hip_bf16.h>

#define N_NODES 20000
#define B 4
#define H 128
#define I_DIM 64
#define E_MAX 320000
#define CAP 64              // padded CSR row capacity == wave width (in-deg ~Poisson(16))

// ---- all scratch in module-static device globals (no d_ws dependence) ----
// g_cnt_dst / g_deg_src are zeroed by the LAST finishing block of fused_kernel
// (race-free: the zeroing block runs only after every block's atomicAdd on
// g_done, which follows all of that block's reads). Zero-init at load makes
// run 0 correct as well.
__device__ int   g_cnt_dst[N_NODES];        // atomic cursor == final in-degree
__device__ int   g_deg_src[N_NODES];        // out-degree
__device__ int   g_csr[N_NODES * CAP];      // padded CSR: row n at n*CAP, 5.12 MB
__device__ int   g_done;                    // last-block detector
__device__ float g_xg[4 * B * H];
// batch-interleaved bf16 copy of h_prev (raw, unscaled):
// g_hs[n*H+h] = {bf16 h_prev[b][n][h], b=0..3}
__device__ uint2 g_hs[N_NODES * H];

// ---- prep (single kernel, block-range dispatched): ----
// pack:  blocks [0, 10000)          — h_prev -> bf16 x4 batches
// place: blocks [10000, 10000+eb)   — padded-CSR scatter via atomic cursor
//                                     (cursor doubles as in-degree; NO scan)
// xgate: blocks [10000+eb, +8)      — x @ W_g + b_g for 4 gates x 4 batches
__global__ __launch_bounds__(256)
void prep_kernel(const float* __restrict__ h_prev,
                 const int* __restrict__ src, const int* __restrict__ dst, int E,
                 int place_blocks,
                 const float* __restrict__ x,
                 const float* __restrict__ Wi, const float* __restrict__ bi,
                 const float* __restrict__ Wf, const float* __restrict__ bf_,
                 const float* __restrict__ Wo, const float* __restrict__ bo,
                 const float* __restrict__ Wc, const float* __restrict__ bc) {
    const int PACK_BLKS = (N_NODES * H) / 256;   // 10000, exact
    int blk = blockIdx.x;
    int t = threadIdx.x;

    if (blk < PACK_BLKS) {
        int i = blk * 256 + t;                    // (n*H + h), always in range
        const long stride = (long)N_NODES * H;
        float v0 = h_prev[i];
        float v1 = h_prev[i + stride];
        float v2 = h_prev[i + 2 * stride];
        float v3 = h_prev[i + 3 * stride];
        __hip_bfloat162 p01 = __float22bfloat162_rn(make_float2(v0, v1));
        __hip_bfloat162 p23 = __float22bfloat162_rn(make_float2(v2, v3));
        uint2 wv;
        wv.x = *reinterpret_cast<unsigned int*>(&p01);
        wv.y = *reinterpret_cast<unsigned int*>(&p23);
        g_hs[i] = wv;
    } else if (blk < PACK_BLKS + place_blocks) {
        int e = (blk - PACK_BLKS) * 256 + t;
        if (e < E) {
            int d = dst[e];
            int s = src[e];
            int slot = atomicAdd(&g_cnt_dst[d], 1);
            if (slot < CAP) g_csr[(d << 6) + slot] = s;
            atomicAdd(&g_deg_src[s], 1);
        }
    } else {
        int bid = blk - PACK_BLKS - place_blocks; // 0..7
        int g = bid >> 1;                         // gate 0..3
        int b = ((bid & 1) << 1) | (t >> 7);      // batch 0..3
        int h = t & 127;
        const float* W;
        const float* bb;
        switch (g) {
            case 0: W = Wi; bb = bi; break;
            case 1: W = Wf; bb = bf_; break;
            case 2: W = Wo; bb = bo; break;
            default: W = Wc; bb = bc; break;
        }
        float acc = bb[h];
#pragma unroll
        for (int i = 0; i < I_DIM; i++)
            acc += x[b * I_DIM + i] * W[i * H + h];
        g_xg[(g * B + b) * H + h] = acc;
    }
}

__device__ __forceinline__ float fast_sigmoid(float z) {
    return 1.f / (1.f + __expf(-z));
}
__device__ __forceinline__ float fast_tanh(float z) {
    // 1 - 2/(e^{2z}+1): e^{2z}->inf => 1; e^{2z}->0 => -1. No inf/inf NaN path.
    return 1.f - 2.f / (__expf(2.f * z) + 1.f);
}

// ------- fused: padded-CSR gather (bf16 table) + dn + Wg matvec + LSTM ---------
__global__ __launch_bounds__(128)
void fused_kernel(const float* __restrict__ Wg, const float* __restrict__ bg,
                  const float* __restrict__ c_prev,
                  float* __restrict__ out_h, float* __restrict__ out_c) {
    int n = blockIdx.x;
    int h = threadIdx.x;
    int lane = h & 63;
    int cnt = g_cnt_dst[n];                    // own-block counter: race-free
    float dd = rsqrtf(fmaxf((float)cnt, 1.0f));
    if (cnt > CAP) cnt = CAP;                  // never triggers (safety)
    int beg = n << 6;

    // Lane-parallel prefetch: CAP == 64 == wave width, so lane l holds edge
    // l's row base and dn_src scale in registers after ONE parallel round
    // trip. The main loop gets them via wave-uniform __shfl (VALU only) --
    // no csr/deg loads on the critical path, and rsqrt runs once per lane
    // instead of once per edge.
    int s_l = g_csr[beg + (lane < cnt ? lane : 0)];   // stale slots hold valid ids (zero-init run 0)
    float sc_l = rsqrtf(fmaxf((float)g_deg_src[s_l], 1.0f));
    int base_l = s_l << 7;                     // s * H

    float a0 = 0.f, a1 = 0.f, a2 = 0.f, a3 = 0.f;

#define ACC(w, sc) { \
        __hip_bfloat162 p01 = *reinterpret_cast<__hip_bfloat162*>(&(w).x); \
        __hip_bfloat162 p23 = *reinterpret_cast<__hip_bfloat162*>(&(w).y); \
        float2 f01 = __bfloat1622float2(p01); \
        float2 f23 = __bfloat1622float2(p23); \
        a0 += f01.x * (sc); a1 += f01.y * (sc); a2 += f23.x * (sc); a3 += f23.y * (sc); }

    int j = 0;
    for (; j + 8 <= cnt; j += 8) {
        int   b0 = __shfl(base_l, j + 0); float c0 = __shfl(sc_l, j + 0);
        int   b1 = __shfl(base_l, j + 1); float c1 = __shfl(sc_l, j + 1);
        int   b2 = __shfl(base_l, j + 2); float c2 = __shfl(sc_l, j + 2);
        int   b3 = __shfl(base_l, j + 3); float c3 = __shfl(sc_l, j + 3);
        int   b4 = __shfl(base_l, j + 4); float c4 = __shfl(sc_l, j + 4);
        int   b5 = __shfl(base_l, j + 5); float c5 = __shfl(sc_l, j + 5);
        int   b6 = __shfl(base_l, j + 6); float c6 = __shfl(sc_l, j + 6);
        int   b7 = __shfl(base_l, j + 7); float c7 = __shfl(sc_l, j + 7);
        uint2 w0 = g_hs[b0 + h];
        uint2 w1 = g_hs[b1 + h];
        uint2 w2 = g_hs[b2 + h];
        uint2 w3 = g_hs[b3 + h];
        uint2 w4 = g_hs[b4 + h];
        uint2 w5 = g_hs[b5 + h];
        uint2 w6 = g_hs[b6 + h];
        uint2 w7 = g_hs[b7 + h];
        ACC(w0, c0); ACC(w1, c1); ACC(w2, c2); ACC(w3, c3);
        ACC(w4, c4); ACC(w5, c5); ACC(w6, c6); ACC(w7, c7);
    }
    for (; j < cnt; j++) {
        int   bj = __shfl(base_l, j);
        float cj = __shfl(sc_l, j);
        uint2 w  = g_hs[bj + h];
        ACC(w, cj);
    }
#undef ACC

    __shared__ float4 arow4[H];
    arow4[h] = make_float4(a0 * dd, a1 * dd, a2 * dd, a3 * dd);
    __syncthreads();

    float g0 = 0.f, g1 = 0.f, g2 = 0.f, g3 = 0.f;
#pragma unroll 8
    for (int k = 0; k < H; k++) {
        float w = Wg[k * H + h];               // coalesced, L1/L2-resident
        float4 a = arow4[k];                   // broadcast ds_read
        g0 += a.x * w;
        g1 += a.y * w;
        g2 += a.z * w;
        g3 += a.w * w;
    }
    float bgh = bg[h];

    const long stride = (long)N_NODES * H;
    float gh_arr[B] = {g0 + bgh, g1 + bgh, g2 + bgh, g3 + bgh};
#pragma unroll
    for (int b = 0; b < B; b++) {
        float gh = gh_arr[b];
        float xi = g_xg[(0 * B + b) * H + h];
        float xf = g_xg[(1 * B + b) * H + h];
        float xo = g_xg[(2 * B + b) * H + h];
        float xc = g_xg[(3 * B + b) * H + h];

        float it = fast_sigmoid(xi + gh);
        float ft = fast_sigmoid(xf + gh);
        float ot = fast_sigmoid(xo + gh);
        float ct = fast_tanh(xc + gh);

        long idx = (long)b * stride + (long)n * H + h;
        float cp = c_prev[idx];
        float c  = ft * cp + it * ct;
        float ho = ot * fast_tanh(c);

        out_h[idx] = ho;
        out_c[idx] = c;
    }

    // ---- last-block zeroing of the atomic counters (race-free) ----
    // Every block's g_deg_src/g_cnt_dst reads are consumed before its
    // atomicAdd below; the sole zeroing block runs only after ALL blocks
    // have arrived, so no concurrent reader exists.
    __threadfence();
    __shared__ int amlast;
    if (h == 0) {
        int old = atomicAdd(&g_done, 1);
        amlast = (old == (int)gridDim.x - 1) ? 1 : 0;
    }
    __syncthreads();
    if (amlast) {
        int4 z = make_int4(0, 0, 0, 0);
        int4* cd = reinterpret_cast<int4*>(g_cnt_dst);
        int4* ds = reinterpret_cast<int4*>(g_deg_src);
        for (int i = h; i < N_NODES / 4; i += 128) {
            cd[i] = z;
            ds[i] = z;
        }
        if (h == 0) g_done = 0;
    }
}

extern "C" void kernel_launch(void* const* d_in, const int* in_sizes, int n_in,
                              void* d_out, int out_size, void* d_ws, size_t ws_size,
                              hipStream_t stream) {
    const float* x      = (const float*)d_in[0];
    const float* h_prev = (const float*)d_in[1];
    const float* c_prev = (const float*)d_in[2];
    const int* src = (const int*)d_in[3];
    const int* dst = (const int*)d_in[4];
    const float* Wi = (const float*)d_in[5];
    const float* bi = (const float*)d_in[6];
    const float* Wf = (const float*)d_in[7];
    const float* bf_ = (const float*)d_in[8];
    const float* Wo = (const float*)d_in[9];
    const float* bo = (const float*)d_in[10];
    const float* Wc = (const float*)d_in[11];
    const float* bc = (const float*)d_in[12];
    const float* Wg = (const float*)d_in[13];
    const float* bg = (const float*)d_in[14];

    int E = in_sizes[3];
    if (E > E_MAX) E = E_MAX;   // static scratch bound (setup fixes E=320000)
    int eb = (E + 255) / 256;
    const int PACK_BLKS = (N_NODES * H) / 256;   // 10000

    prep_kernel<<<PACK_BLKS + eb + 8, 256, 0, stream>>>(
        h_prev, src, dst, E, eb,
        x, Wi, bi, Wf, bf_, Wo, bo, Wc, bc);

    float* out_h = (float*)d_out;
    float* out_c = out_h + (long)B * N_NODES * H;
    fused_kernel<<<N_NODES, 128, 0, stream>>>(Wg, bg, c_prev, out_h, out_c);
}

// Round 5
// 305.031 us; speedup vs baseline: 5.8958x; 5.8958x over previous
//
#include <hip/hip_runtime.h>
#include <hip/hip_bf16.h>

#define N_NODES 20000
#define B 4
#define H 128
#define I_DIM 64
#define E_MAX 320000
#define CAP 64              // padded CSR row capacity (in-deg ~Poisson(16); P(>63) ~ e^-40)

// ---- all scratch in module-static device globals (no d_ws dependence) ----
// g_cnt_dst[n] / g_deg_src[n] are zeroed by fused_kernel block n's OWN epilogue
// (fused never reads any other block's counters -> race-free, no contention).
// Zero-init at module load makes run 0 correct as well.
__device__ int   g_cnt_dst[N_NODES];        // atomic cursor == final in-degree
__device__ int   g_deg_src[N_NODES];        // out-degree
__device__ int   g_csr[N_NODES * CAP];      // padded CSR: row n at n*CAP, 5.12 MB
__device__ float g_xg[4 * B * H];
// batch-interleaved bf16 copy of h_prev, PRE-SCALED by dn_src = rsqrt(out_deg):
// g_hs[n*H+h] = {bf16 (h_prev[b][n][h] * dn_src[n]), b=0..3}
__device__ uint2 g_hs[N_NODES * H];

// ---- K1: src-degree histogram (L2-resident 80KB table) + xgate ----
// blocks [0, eb)      : atomic out-degree count
// blocks [eb, eb+8)   : x @ W_g + b_g for 4 gates x 4 batches
__global__ __launch_bounds__(256)
void degree_kernel(const int* __restrict__ src, int E, int eb,
                   const float* __restrict__ x,
                   const float* __restrict__ Wi, const float* __restrict__ bi,
                   const float* __restrict__ Wf, const float* __restrict__ bf_,
                   const float* __restrict__ Wo, const float* __restrict__ bo,
                   const float* __restrict__ Wc, const float* __restrict__ bc) {
    int blk = blockIdx.x;
    int t = threadIdx.x;
    if (blk < eb) {
        int e = blk * 256 + t;
        if (e < E) atomicAdd(&g_deg_src[src[e]], 1);
    } else {
        int bid = blk - eb;                       // 0..7
        int g = bid >> 1;                         // gate 0..3
        int b = ((bid & 1) << 1) | (t >> 7);      // batch 0..3
        int h = t & 127;
        const float* W;
        const float* bb;
        switch (g) {
            case 0: W = Wi; bb = bi; break;
            case 1: W = Wf; bb = bf_; break;
            case 2: W = Wo; bb = bo; break;
            default: W = Wc; bb = bc; break;
        }
        float acc = bb[h];
#pragma unroll
        for (int i = 0; i < I_DIM; i++)
            acc += x[b * I_DIM + i] * W[i * H + h];
        g_xg[(g * B + b) * H + h] = acc;
    }
}

// ---- K2: pack (dn_src folded into bf16) + padded-CSR place ----
// pack:  blocks [0, 10000)          — h_prev * dn_src -> bf16 x4 batches
// place: blocks [10000, 10000+eb)   — scatter via atomic cursor (== in-degree)
__global__ __launch_bounds__(256)
void mid_kernel(const float* __restrict__ h_prev,
                const int* __restrict__ src, const int* __restrict__ dst, int E) {
    const int PACK_BLKS = (N_NODES * H) / 256;   // 10000, exact
    int blk = blockIdx.x;
    int t = threadIdx.x;

    if (blk < PACK_BLKS) {
        int i = blk * 256 + t;                    // (n*H + h), always in range
        int n = i >> 7;                           // H = 128
        float sc = rsqrtf(fmaxf((float)g_deg_src[n], 1.0f));
        const long stride = (long)N_NODES * H;
        float v0 = h_prev[i] * sc;
        float v1 = h_prev[i + stride] * sc;
        float v2 = h_prev[i + 2 * stride] * sc;
        float v3 = h_prev[i + 3 * stride] * sc;
        __hip_bfloat162 p01 = __float22bfloat162_rn(make_float2(v0, v1));
        __hip_bfloat162 p23 = __float22bfloat162_rn(make_float2(v2, v3));
        uint2 wv;
        wv.x = *reinterpret_cast<unsigned int*>(&p01);
        wv.y = *reinterpret_cast<unsigned int*>(&p23);
        g_hs[i] = wv;
    } else {
        int e = (blk - PACK_BLKS) * 256 + t;
        if (e < E) {
            int d = dst[e];
            int slot = atomicAdd(&g_cnt_dst[d], 1);
            if (slot < CAP) g_csr[(d << 6) + slot] = src[e];
        }
    }
}

__device__ __forceinline__ float fast_sigmoid(float z) {
    return 1.f / (1.f + __expf(-z));
}
__device__ __forceinline__ float fast_tanh(float z) {
    // 1 - 2/(e^{2z}+1): e^{2z}->inf => 1; e^{2z}->0 => -1. No inf/inf NaN path.
    return 1.f - 2.f / (__expf(2.f * z) + 1.f);
}

// ------- K3 fused: padded-CSR gather (bf16 table) + Wg matvec + LSTM ---------
__global__ __launch_bounds__(128)
void fused_kernel(const float* __restrict__ Wg, const float* __restrict__ bg,
                  const float* __restrict__ c_prev,
                  float* __restrict__ out_h, float* __restrict__ out_c) {
    int n = blockIdx.x;
    int h = threadIdx.x;
    int cnt = g_cnt_dst[n];                    // own-block counter: race-free
    float dd = rsqrtf(fmaxf((float)cnt, 1.0f));
    if (cnt > CAP) cnt = CAP;                  // never triggers (safety)
    int beg = n << 6;

    // Stage the row's indices in LDS once (one coalesced parallel load by
    // wave 0, pre-shifted to g_hs row bases). The gather loop then fetches
    // them via broadcast ds_read (~120cy, conflict-free) instead of global
    // index loads (~200-300cy) per iteration -> shorter dependent chain.
    __shared__ int sbase[CAP];
    if (h < CAP) {
        int s = g_csr[beg + (h < cnt ? h : 0)];   // always a valid address
        sbase[h] = s << 7;                        // s * H
    }
    __syncthreads();

    float a0 = 0.f, a1 = 0.f, a2 = 0.f, a3 = 0.f;

#define ACC(w) { \
        __hip_bfloat162 p01 = *reinterpret_cast<__hip_bfloat162*>(&(w).x); \
        __hip_bfloat162 p23 = *reinterpret_cast<__hip_bfloat162*>(&(w).y); \
        float2 f01 = __bfloat1622float2(p01); \
        float2 f23 = __bfloat1622float2(p23); \
        a0 += f01.x; a1 += f01.y; a2 += f23.x; a3 += f23.y; }

    // 8-wide unroll: 8 row bases from LDS, then 8 independent 512B/wave
    // row loads in flight before any consumption (avg degree 16).
    int j = 0;
    for (; j + 8 <= cnt; j += 8) {
        int b0 = sbase[j];
        int b1 = sbase[j + 1];
        int b2 = sbase[j + 2];
        int b3 = sbase[j + 3];
        int b4 = sbase[j + 4];
        int b5 = sbase[j + 5];
        int b6 = sbase[j + 6];
        int b7 = sbase[j + 7];
        uint2 w0 = g_hs[b0 + h];
        uint2 w1 = g_hs[b1 + h];
        uint2 w2 = g_hs[b2 + h];
        uint2 w3 = g_hs[b3 + h];
        uint2 w4 = g_hs[b4 + h];
        uint2 w5 = g_hs[b5 + h];
        uint2 w6 = g_hs[b6 + h];
        uint2 w7 = g_hs[b7 + h];
        ACC(w0); ACC(w1); ACC(w2); ACC(w3);
        ACC(w4); ACC(w5); ACC(w6); ACC(w7);
    }
    for (; j + 4 <= cnt; j += 4) {
        int b0 = sbase[j];
        int b1 = sbase[j + 1];
        int b2 = sbase[j + 2];
        int b3 = sbase[j + 3];
        uint2 w0 = g_hs[b0 + h];
        uint2 w1 = g_hs[b1 + h];
        uint2 w2 = g_hs[b2 + h];
        uint2 w3 = g_hs[b3 + h];
        ACC(w0); ACC(w1); ACC(w2); ACC(w3);
    }
    for (; j < cnt; j++) {
        uint2 w = g_hs[sbase[j] + h];
        ACC(w);
    }
#undef ACC

    __shared__ float4 arow4[H];
    arow4[h] = make_float4(a0 * dd, a1 * dd, a2 * dd, a3 * dd);
    __syncthreads();

    float g0 = 0.f, g1 = 0.f, g2 = 0.f, g3 = 0.f;
#pragma unroll 8
    for (int k = 0; k < H; k++) {
        float w = Wg[k * H + h];               // coalesced, L1/L2-resident
        float4 a = arow4[k];                   // broadcast ds_read
        g0 += a.x * w;
        g1 += a.y * w;
        g2 += a.z * w;
        g3 += a.w * w;
    }
    float bgh = bg[h];

    const long stride = (long)N_NODES * H;
    float gh_arr[B] = {g0 + bgh, g1 + bgh, g2 + bgh, g3 + bgh};
#pragma unroll
    for (int b = 0; b < B; b++) {
        float gh = gh_arr[b];
        float xi = g_xg[(0 * B + b) * H + h];
        float xf = g_xg[(1 * B + b) * H + h];
        float xo = g_xg[(2 * B + b) * H + h];
        float xc = g_xg[(3 * B + b) * H + h];

        float it = fast_sigmoid(xi + gh);
        float ft = fast_sigmoid(xf + gh);
        float ot = fast_sigmoid(xo + gh);
        float ct = fast_tanh(xc + gh);

        long idx = (long)b * stride + (long)n * H + h;
        float cp = c_prev[idx];
        float c  = ft * cp + it * ct;
        float ho = ot * fast_tanh(c);

        out_h[idx] = ho;
        out_c[idx] = c;
    }

    // Own-block counter zeroing: fused reads only g_cnt_dst[n] (own block)
    // and never reads g_deg_src, so no other block can observe these writes
    // mid-use. Next launch's kernels are stream-ordered after this one.
    if (h == 0)  g_cnt_dst[n] = 0;
    if (h == 64) g_deg_src[n] = 0;
}

extern "C" void kernel_launch(void* const* d_in, const int* in_sizes, int n_in,
                              void* d_out, int out_size, void* d_ws, size_t ws_size,
                              hipStream_t stream) {
    const float* x      = (const float*)d_in[0];
    const float* h_prev = (const float*)d_in[1];
    const float* c_prev = (const float*)d_in[2];
    const int* src = (const int*)d_in[3];
    const int* dst = (const int*)d_in[4];
    const float* Wi = (const float*)d_in[5];
    const float* bi = (const float*)d_in[6];
    const float* Wf = (const float*)d_in[7];
    const float* bf_ = (const float*)d_in[8];
    const float* Wo = (const float*)d_in[9];
    const float* bo = (const float*)d_in[10];
    const float* Wc = (const float*)d_in[11];
    const float* bc = (const float*)d_in[12];
    const float* Wg = (const float*)d_in[13];
    const float* bg = (const float*)d_in[14];

    int E = in_sizes[3];
    if (E > E_MAX) E = E_MAX;   // static scratch bound (setup fixes E=320000)
    int eb = (E + 255) / 256;
    const int PACK_BLKS = (N_NODES * H) / 256;   // 10000

    degree_kernel<<<eb + 8, 256, 0, stream>>>(src, E, eb,
        x, Wi, bi, Wf, bf_, Wo, bo, Wc, bc);
    mid_kernel<<<PACK_BLKS + eb, 256, 0, stream>>>(h_prev, src, dst, E);

    float* out_h = (float*)d_out;
    float* out_c = out_h + (long)B * N_NODES * H;
    fused_kernel<<<N_NODES, 128, 0, stream>>>(Wg, bg, c_prev, out_h, out_c);
}